// Round 4
// baseline (424.227 us; speedup 1.0000x reference)
//
#include <hip/hip_runtime.h>
#include <hip/hip_bf16.h>

#define VOCAB 50257
#define EMBED 128
#define BATCH 4096
#define CTX   8

#define BM 128
#define BN 64
#define NXT 786            // col tiles of 64 (785*64+17 = 50257)
#define VPAD 50304         // 786*64
#define LDSP 136           // transpose-stage LDS row stride (ushort units)

typedef __attribute__((ext_vector_type(8))) short bf16x8;
typedef __attribute__((ext_vector_type(4))) float f32x4;

static __device__ __forceinline__ ushort f2bf(float f) {
  __hip_bfloat16 h = __float2bfloat16(f);
  return *reinterpret_cast<ushort*>(&h);
}

// ---------------- Kernel 1: embedding bag -> bf16 word_emb ----------------
__global__ __launch_bounds__(256) void embed_bag_kernel(
    const int* __restrict__ idx, const float* __restrict__ Wp,
    __hip_bfloat16* __restrict__ emb) {
  int wave = threadIdx.x >> 6;
  int lane = threadIdx.x & 63;
  int row  = blockIdx.x * 4 + wave;
  const int* ri = idx + row * CTX;
  int e0 = lane * 2;
  float s0 = 0.f, s1 = 0.f;
#pragma unroll
  for (int c = 0; c < CTX; ++c) {
    int w = ri[c];
    float2 wv = *reinterpret_cast<const float2*>(Wp + (size_t)w * EMBED + e0);
    s0 += wv.x; s1 += wv.y;
  }
  __hip_bfloat162 pv;
  pv.x = __float2bfloat16(s0);
  pv.y = __float2bfloat16(s1);
  *reinterpret_cast<__hip_bfloat162*>(emb + (size_t)row * EMBED + e0) = pv;
}

// ------- Kernel 1b: W_pred [128][50257]f32 -> Btf fragment-ordered bf16 -------
// Btf[strip x][instr=kq*4+n][lane][8]: lane reads exactly its MFMA B-fragment,
// so GEMM B loads are fully coalesced (1KB per wave instruction).
__global__ __launch_bounds__(256) void transpose_b_kernel(
    const float* __restrict__ Bm, ushort* __restrict__ Btf) {
  __shared__ ushort Bs[BN * LDSP];
  int x = blockIdx.x;
  int cbase = x * BN;
  int tid = threadIdx.x;
  bool edge = (cbase + BN > VOCAB);
#pragma unroll
  for (int i = 0; i < 8; ++i) {
    int c  = tid + i * 256;             // [0,2048)
    int e  = c >> 4;                    // k-row 0..127
    int v4 = (c & 15) << 2;             // col offset
    int col = cbase + v4;
    float4 b;
    if (!edge) {
      b = *reinterpret_cast<const float4*>(Bm + (size_t)e * VOCAB + col);
    } else {
      b.x = (col + 0 < VOCAB) ? Bm[(size_t)e * VOCAB + col + 0] : 0.f;
      b.y = (col + 1 < VOCAB) ? Bm[(size_t)e * VOCAB + col + 1] : 0.f;
      b.z = (col + 2 < VOCAB) ? Bm[(size_t)e * VOCAB + col + 2] : 0.f;
      b.w = (col + 3 < VOCAB) ? Bm[(size_t)e * VOCAB + col + 3] : 0.f;
    }
    Bs[(v4 + 0) * LDSP + e] = f2bf(b.x);
    Bs[(v4 + 1) * LDSP + e] = f2bf(b.y);
    Bs[(v4 + 2) * LDSP + e] = f2bf(b.z);
    Bs[(v4 + 3) * LDSP + e] = f2bf(b.w);
  }
  __syncthreads();
  int lane = tid & 63, wv = tid >> 6;
  int lr = lane & 15, lg = lane >> 4;
#pragma unroll
  for (int p = 0; p < 4; ++p) {
    int instr = p * 4 + wv;
    int kq = instr >> 2, n = instr & 3;
    int v  = n * 16 + lr;
    int e0 = kq * 32 + lg * 8;
    uint4 val = *reinterpret_cast<const uint4*>(&Bs[v * LDSP + e0]);
    *reinterpret_cast<uint4*>(Btf + (size_t)x * 8192 + instr * 512 + lane * 8) = val;
  }
}

// ---------------- Kernel 2: persistent barrier-free GEMM ----------------
// grid = 8 xcd * 32 y * 3 = 768 blocks (3/CU). Each block: A frags once,
// then streams ~33 XCD-local column strips: 16 coalesced B loads, 32 MFMA,
// 32 stores. No LDS, no barriers.
__global__ __launch_bounds__(256, 3) void gemm3_kernel(
    const ushort* __restrict__ A,       // emb bf16 [4096][128]
    const ushort* __restrict__ Btf,     // [786][16][64][8] bf16
    float* __restrict__ C) {
  int bid = blockIdx.x;
  int k8  = bid & 7;                    // XCD
  int j   = bid >> 3;                   // 0..95
  int s   = j % 3;
  int y   = j / 3;                      // 0..31
  int ts  = (k8 < 2) ? 99 : 98;         // strips for this xcd chain

  int tid  = threadIdx.x;
  int lane = tid & 63;
  int wv   = tid >> 6;
  int lr   = lane & 15;
  int lg   = lane >> 4;
  int r0   = wv * 32;

  // A fragments once (L2-resident)
  const ushort* Ag = A + (size_t)(y * BM) * EMBED;
  bf16x8 af[2][4];
#pragma unroll
  for (int m = 0; m < 2; ++m)
#pragma unroll
    for (int kq = 0; kq < 4; ++kq)
      af[m][kq] = *reinterpret_cast<const bf16x8*>(
          Ag + (r0 + m * 16 + lr) * EMBED + kq * 32 + lg * 8);

  size_t crow0 = (size_t)y * BM + r0;
  float* Crow0 = C + (crow0 + 0 * 16 + lg * 4) * (size_t)VOCAB;
  float* Crow1 = C + (crow0 + 1 * 16 + lg * 4) * (size_t)VOCAB;

  for (int t = s; t < ts; t += 3) {
    int x = k8 + t * 8;
    const ushort* Bg = Btf + (size_t)x * 8192 + lane * 8;

    bf16x8 bc[4][4];                    // [n][kq]
#pragma unroll
    for (int kq = 0; kq < 4; ++kq)
#pragma unroll
      for (int n = 0; n < 4; ++n)
        bc[n][kq] = *reinterpret_cast<const bf16x8*>(Bg + (kq * 4 + n) * 512);

    f32x4 acc[2][4] = {};
#pragma unroll
    for (int kq = 0; kq < 4; ++kq)
#pragma unroll
      for (int m = 0; m < 2; ++m)
#pragma unroll
        for (int n = 0; n < 4; ++n)
          acc[m][n] = __builtin_amdgcn_mfma_f32_16x16x32_bf16(
              af[m][kq], bc[n][kq], acc[m][n], 0, 0, 0);

    int cc0 = x * BN;
    if (x != NXT - 1) {
#pragma unroll
      for (int n = 0; n < 4; ++n) {
        int colc = cc0 + n * 16 + lr;
#pragma unroll
        for (int q = 0; q < 4; ++q) {
          Crow0[(size_t)q * VOCAB + colc] = acc[0][n][q];
          Crow1[(size_t)q * VOCAB + colc] = acc[1][n][q];
        }
      }
    } else {
#pragma unroll
      for (int n = 0; n < 4; ++n) {
        int colc = cc0 + n * 16 + lr;
        if (colc < VOCAB) {
#pragma unroll
          for (int q = 0; q < 4; ++q) {
            Crow0[(size_t)q * VOCAB + colc] = acc[0][n][q];
            Crow1[(size_t)q * VOCAB + colc] = acc[1][n][q];
          }
        }
      }
    }
  }
}

// ---------------- Fallback GEMM (R2 style) if ws too small ----------------
#define FLDSP 132
__global__ __launch_bounds__(256, 4) void gemm_kernel(
    const __hip_bfloat16* __restrict__ A,
    const float* __restrict__ Bm,
    float* __restrict__ C) {
  __shared__ char BsRaw[BN * FLDSP * 2];
  int bid = blockIdx.x;
  int k8  = bid & 7;
  int j   = bid >> 3;
  int t   = j >> 5;
  int y   = j & 31;
  int x   = k8 + t * 8;
  if (x >= NXT) return;

  int tid  = threadIdx.x;
  int lane = tid & 63;
  int wv   = tid >> 6;
  int lr   = lane & 15;
  int lg   = lane >> 4;
  int r0   = wv * 32;

  const ushort* Ag = reinterpret_cast<const ushort*>(A) + (size_t)(y * BM) * EMBED;
  uint4 a_raw[2][4];
#pragma unroll
  for (int m = 0; m < 2; ++m)
#pragma unroll
    for (int kq = 0; kq < 4; ++kq)
      a_raw[m][kq] = *reinterpret_cast<const uint4*>(
          Ag + (r0 + m * 16 + lr) * EMBED + kq * 32 + lg * 8);

  int cbase = x * BN;
  bool edge = (x == NXT - 1);
  float4 bb[8];
#pragma unroll
  for (int i = 0; i < 8; ++i) {
    int c  = tid + i * 256;
    int e  = c >> 4;
    int v4 = (c & 15) << 2;
    int col = cbase + v4;
    if (!edge) {
      bb[i] = *reinterpret_cast<const float4*>(Bm + (size_t)e * VOCAB + col);
    } else {
      bb[i].x = (col + 0 < VOCAB) ? Bm[(size_t)e * VOCAB + col + 0] : 0.f;
      bb[i].y = (col + 1 < VOCAB) ? Bm[(size_t)e * VOCAB + col + 1] : 0.f;
      bb[i].z = (col + 2 < VOCAB) ? Bm[(size_t)e * VOCAB + col + 2] : 0.f;
      bb[i].w = (col + 3 < VOCAB) ? Bm[(size_t)e * VOCAB + col + 3] : 0.f;
    }
  }
#pragma unroll
  for (int i = 0; i < 8; ++i) {
    int c  = tid + i * 256;
    int e  = c >> 4;
    int v4 = (c & 15) << 2;
    float vals[4] = {bb[i].x, bb[i].y, bb[i].z, bb[i].w};
#pragma unroll
    for (int jj = 0; jj < 4; ++jj) {
      int v   = v4 + jj;
      int off = v * (FLDSP * 2) + ((e * 2) ^ ((v & 28) << 2));
      *reinterpret_cast<ushort*>(BsRaw + off) = f2bf(vals[jj]);
    }
  }
  __syncthreads();

  f32x4 acc[2][4] = {};
#pragma unroll
  for (int kq = 0; kq < 4; ++kq) {
    int ebyte = (kq * 32 + lg * 8) * 2;
    bf16x8 bfr[4];
#pragma unroll
    for (int n = 0; n < 4; ++n) {
      int v   = n * 16 + lr;
      int off = v * (FLDSP * 2) + (ebyte ^ ((v & 28) << 2));
      bfr[n] = *reinterpret_cast<const bf16x8*>(BsRaw + off);
    }
#pragma unroll
    for (int m = 0; m < 2; ++m) {
      bf16x8 af = __builtin_bit_cast(bf16x8, a_raw[m][kq]);
#pragma unroll
      for (int n = 0; n < 4; ++n)
        acc[m][n] = __builtin_amdgcn_mfma_f32_16x16x32_bf16(af, bfr[n], acc[m][n], 0, 0, 0);
    }
  }

  size_t crow0 = (size_t)y * BM + r0;
#pragma unroll
  for (int m = 0; m < 2; ++m) {
#pragma unroll
    for (int n = 0; n < 4; ++n) {
      int colc = cbase + n * 16 + lr;
      if (colc < VOCAB) {
        float* cp = C + (crow0 + m * 16 + lg * 4) * (size_t)VOCAB + colc;
#pragma unroll
        for (int q = 0; q < 4; ++q)
          cp[(size_t)q * VOCAB] = acc[m][n][q];
      }
    }
  }
}

extern "C" void kernel_launch(void* const* d_in, const int* in_sizes, int n_in,
                              void* d_out, int out_size, void* d_ws, size_t ws_size,
                              hipStream_t stream) {
  const int*   idx    = (const int*)d_in[0];
  const float* W_proj = (const float*)d_in[1];
  const float* W_pred = (const float*)d_in[2];
  float*       out    = (float*)d_out;

  __hip_bfloat16* emb = (__hip_bfloat16*)d_ws;                 // 1 MB
  ushort* Btf = (ushort*)((char*)d_ws + (size_t)1048576);      // 12.9 MB
  const size_t needed = (size_t)1048576 + (size_t)VPAD * EMBED * 2;

  embed_bag_kernel<<<BATCH / 4, 256, 0, stream>>>(idx, W_proj, emb);

  if (ws_size >= needed) {
    transpose_b_kernel<<<NXT, 256, 0, stream>>>(W_pred, Btf);
    gemm3_kernel<<<768, 256, 0, stream>>>((const ushort*)emb, Btf, out);
  } else {
    int strips = (NXT + 7) / 8;
    int grid = 8 * strips * 32;
    gemm_kernel<<<grid, 256, 0, stream>>>(emb, W_pred, out);
  }
}

// Round 5
// 399.776 us; speedup vs baseline: 1.0612x; 1.0612x over previous
//
#include <hip/hip_runtime.h>
#include <hip/hip_bf16.h>

#define VOCAB 50257
#define EMBED 128
#define BATCH 4096
#define CTX   8

#define BM 128
#define NXT 786            // 64-col strips
#define NSS 197            // 256-col super-strips (196 full + 1 partial)
#define VPAD 50304
#define LDSP 136

typedef __attribute__((ext_vector_type(8))) short bf16x8;
typedef __attribute__((ext_vector_type(4))) float f32x4;
typedef float f32x4u __attribute__((ext_vector_type(4), aligned(4)));

static __device__ __forceinline__ ushort f2bf(float f) {
  __hip_bfloat16 h = __float2bfloat16(f);
  return *reinterpret_cast<ushort*>(&h);
}

// ---------------- Kernel 1: embedding bag -> bf16 word_emb ----------------
__global__ __launch_bounds__(256) void embed_bag_kernel(
    const int* __restrict__ idx, const float* __restrict__ Wp,
    __hip_bfloat16* __restrict__ emb) {
  int wave = threadIdx.x >> 6;
  int lane = threadIdx.x & 63;
  int row  = blockIdx.x * 4 + wave;
  const int* ri = idx + row * CTX;
  int e0 = lane * 2;
  float s0 = 0.f, s1 = 0.f;
#pragma unroll
  for (int c = 0; c < CTX; ++c) {
    int w = ri[c];
    float2 wv = *reinterpret_cast<const float2*>(Wp + (size_t)w * EMBED + e0);
    s0 += wv.x; s1 += wv.y;
  }
  __hip_bfloat162 pv;
  pv.x = __float2bfloat16(s0);
  pv.y = __float2bfloat16(s1);
  *reinterpret_cast<__hip_bfloat162*>(emb + (size_t)row * EMBED + e0) = pv;
}

// ------- Kernel 1b: W_pred [128][50257]f32 -> Btf fragment-ordered bf16 -------
// Btf[strip][instr=kq*4+nf][lane][8]
__global__ __launch_bounds__(256) void transpose_b_kernel(
    const float* __restrict__ Bm, ushort* __restrict__ Btf) {
  __shared__ ushort Bs[64 * LDSP];
  int x = blockIdx.x;
  int cbase = x * 64;
  int tid = threadIdx.x;
  bool edge = (cbase + 64 > VOCAB);
#pragma unroll
  for (int i = 0; i < 8; ++i) {
    int c  = tid + i * 256;
    int e  = c >> 4;
    int v4 = (c & 15) << 2;
    int col = cbase + v4;
    float4 b;
    if (!edge) {
      b = *reinterpret_cast<const float4*>(Bm + (size_t)e * VOCAB + col);
    } else {
      b.x = (col + 0 < VOCAB) ? Bm[(size_t)e * VOCAB + col + 0] : 0.f;
      b.y = (col + 1 < VOCAB) ? Bm[(size_t)e * VOCAB + col + 1] : 0.f;
      b.z = (col + 2 < VOCAB) ? Bm[(size_t)e * VOCAB + col + 2] : 0.f;
      b.w = (col + 3 < VOCAB) ? Bm[(size_t)e * VOCAB + col + 3] : 0.f;
    }
    Bs[(v4 + 0) * LDSP + e] = f2bf(b.x);
    Bs[(v4 + 1) * LDSP + e] = f2bf(b.y);
    Bs[(v4 + 2) * LDSP + e] = f2bf(b.z);
    Bs[(v4 + 3) * LDSP + e] = f2bf(b.w);
  }
  __syncthreads();
  int lane = tid & 63, wv = tid >> 6;
  int lr = lane & 15, lg = lane >> 4;
#pragma unroll
  for (int p = 0; p < 4; ++p) {
    int instr = p * 4 + wv;
    int kq = instr >> 2, n = instr & 3;
    int v  = n * 16 + lr;
    int e0 = kq * 32 + lg * 8;
    uint4 val = *reinterpret_cast<const uint4*>(&Bs[v * LDSP + e0]);
    *reinterpret_cast<uint4*>(Btf + (size_t)x * 8192 + instr * 512 + lane * 8) = val;
  }
}

// ---------------- Kernel 2: persistent GEMM, swapped-operand wide stores ----
// 768 blocks = 8 xcd * 32 y * 3 subs (3 blocks/CU). Each block sweeps a
// CONTIGUOUS super-strip range (256 cols/step): per n-step 4 B-loads
// (depth-2 prefetch), 8 MFMA (operands swapped so lane holds 4 consecutive
// vocab cols), 2 dwordx4 stores. Sequential writes restore DRAM page locality.
__global__ __launch_bounds__(256, 3) void gemm4_kernel(
    const ushort* __restrict__ A,
    const ushort* __restrict__ Btf,
    float* __restrict__ C) {
  int bid = blockIdx.x;
  int xcd = bid & 7;
  int j   = bid >> 3;                 // 0..95
  int y   = j & 31;
  int sub = j >> 5;                   // 0..2
  int len   = (xcd < 5) ? 25 : 24;
  int start = xcd * 24 + (xcd < 5 ? xcd : 5);
  int l3 = len / 3, r3 = len % 3;
  int s0   = start + sub * l3 + (sub < r3 ? sub : r3);
  int slen = l3 + (sub < r3 ? 1 : 0);

  int tid  = threadIdx.x;
  int lane = tid & 63;
  int wv   = tid >> 6;
  int lr   = lane & 15;
  int lg   = lane >> 4;
  int r0   = wv * 32;

  const ushort* Ag = A + (size_t)(y * BM) * EMBED;
  bf16x8 af[2][4];
#pragma unroll
  for (int m = 0; m < 2; ++m)
#pragma unroll
    for (int kq = 0; kq < 4; ++kq)
      af[m][kq] = *reinterpret_cast<const bf16x8*>(
          Ag + (r0 + m * 16 + lr) * EMBED + kq * 32 + lg * 8);

  float* Crow0 = C + (size_t)(y * BM + r0 + lr) * VOCAB;
  float* Crow1 = Crow0 + (size_t)16 * VOCAB;

  for (int si = 0; si < slen; ++si) {
    int ss = s0 + si;
    const ushort* Bg = Btf + (size_t)(ss * 4) * 8192 + lane * 8;
    int colbase = ss * 256 + lg * 4;

    if (ss < NSS - 1) {
      bf16x8 buf[3][4];
#pragma unroll
      for (int kq = 0; kq < 4; ++kq)
        buf[0][kq] = *reinterpret_cast<const bf16x8*>(Bg + (kq * 4 + 0) * 512);
#pragma unroll
      for (int kq = 0; kq < 4; ++kq)
        buf[1][kq] = *reinterpret_cast<const bf16x8*>(Bg + (kq * 4 + 1) * 512);
#pragma unroll
      for (int n = 0; n < 16; ++n) {
        int cur = n % 3;
        if (n < 14) {
          int np  = n + 2;
          int nb  = np % 3;
          const ushort* Bp = Bg + (size_t)(np >> 2) * 8192;
#pragma unroll
          for (int kq = 0; kq < 4; ++kq)
            buf[nb][kq] = *reinterpret_cast<const bf16x8*>(Bp + (kq * 4 + (np & 3)) * 512);
        }
        f32x4 acc0 = {0.f, 0.f, 0.f, 0.f};
        f32x4 acc1 = {0.f, 0.f, 0.f, 0.f};
#pragma unroll
        for (int kq = 0; kq < 4; ++kq) {
          acc0 = __builtin_amdgcn_mfma_f32_16x16x32_bf16(buf[cur][kq], af[0][kq], acc0, 0, 0, 0);
          acc1 = __builtin_amdgcn_mfma_f32_16x16x32_bf16(buf[cur][kq], af[1][kq], acc1, 0, 0, 0);
        }
        int col = colbase + n * 16;
        *reinterpret_cast<f32x4u*>(Crow0 + col) = __builtin_bit_cast(f32x4u, acc0);
        *reinterpret_cast<f32x4u*>(Crow1 + col) = __builtin_bit_cast(f32x4u, acc1);
      }
    } else {
      // partial super-strip 196: strips 784 (full) and 785 (17 valid cols)
      for (int n = 0; n < 8; ++n) {
        const ushort* Bp = Bg + (size_t)(n >> 2) * 8192;
        bf16x8 b[4];
#pragma unroll
        for (int kq = 0; kq < 4; ++kq)
          b[kq] = *reinterpret_cast<const bf16x8*>(Bp + (kq * 4 + (n & 3)) * 512);
        f32x4 acc0 = {0.f, 0.f, 0.f, 0.f};
        f32x4 acc1 = {0.f, 0.f, 0.f, 0.f};
#pragma unroll
        for (int kq = 0; kq < 4; ++kq) {
          acc0 = __builtin_amdgcn_mfma_f32_16x16x32_bf16(b[kq], af[0][kq], acc0, 0, 0, 0);
          acc1 = __builtin_amdgcn_mfma_f32_16x16x32_bf16(b[kq], af[1][kq], acc1, 0, 0, 0);
        }
        int col = colbase + n * 16;
        if (col + 3 < VOCAB) {
          *reinterpret_cast<f32x4u*>(Crow0 + col) = __builtin_bit_cast(f32x4u, acc0);
          *reinterpret_cast<f32x4u*>(Crow1 + col) = __builtin_bit_cast(f32x4u, acc1);
        } else {
#pragma unroll
          for (int q = 0; q < 4; ++q) {
            if (col + q < VOCAB) {
              Crow0[col + q] = acc0[q];
              Crow1[col + q] = acc1[q];
            }
          }
        }
      }
    }
  }
}

// ---------------- Fallback GEMM (R2 style) if ws too small ----------------
#define FLDSP 132
__global__ __launch_bounds__(256, 4) void gemm_kernel(
    const __hip_bfloat16* __restrict__ A,
    const float* __restrict__ Bm,
    float* __restrict__ C) {
  __shared__ char BsRaw[64 * FLDSP * 2];
  int bid = blockIdx.x;
  int k8  = bid & 7;
  int j   = bid >> 3;
  int t   = j >> 5;
  int y   = j & 31;
  int x   = k8 + t * 8;
  if (x >= NXT) return;

  int tid  = threadIdx.x;
  int lane = tid & 63;
  int wv   = tid >> 6;
  int lr   = lane & 15;
  int lg   = lane >> 4;
  int r0   = wv * 32;

  const ushort* Ag = reinterpret_cast<const ushort*>(A) + (size_t)(y * BM) * EMBED;
  uint4 a_raw[2][4];
#pragma unroll
  for (int m = 0; m < 2; ++m)
#pragma unroll
    for (int kq = 0; kq < 4; ++kq)
      a_raw[m][kq] = *reinterpret_cast<const uint4*>(
          Ag + (r0 + m * 16 + lr) * EMBED + kq * 32 + lg * 8);

  int cbase = x * 64;
  bool edge = (x == NXT - 1);
  float4 bb[8];
#pragma unroll
  for (int i = 0; i < 8; ++i) {
    int c  = tid + i * 256;
    int e  = c >> 4;
    int v4 = (c & 15) << 2;
    int col = cbase + v4;
    if (!edge) {
      bb[i] = *reinterpret_cast<const float4*>(Bm + (size_t)e * VOCAB + col);
    } else {
      bb[i].x = (col + 0 < VOCAB) ? Bm[(size_t)e * VOCAB + col + 0] : 0.f;
      bb[i].y = (col + 1 < VOCAB) ? Bm[(size_t)e * VOCAB + col + 1] : 0.f;
      bb[i].z = (col + 2 < VOCAB) ? Bm[(size_t)e * VOCAB + col + 2] : 0.f;
      bb[i].w = (col + 3 < VOCAB) ? Bm[(size_t)e * VOCAB + col + 3] : 0.f;
    }
  }
#pragma unroll
  for (int i = 0; i < 8; ++i) {
    int c  = tid + i * 256;
    int e  = c >> 4;
    int v4 = (c & 15) << 2;
    float vals[4] = {bb[i].x, bb[i].y, bb[i].z, bb[i].w};
#pragma unroll
    for (int jj = 0; jj < 4; ++jj) {
      int v   = v4 + jj;
      int off = v * (FLDSP * 2) + ((e * 2) ^ ((v & 28) << 2));
      *reinterpret_cast<ushort*>(BsRaw + off) = f2bf(vals[jj]);
    }
  }
  __syncthreads();

  f32x4 acc[2][4] = {};
#pragma unroll
  for (int kq = 0; kq < 4; ++kq) {
    int ebyte = (kq * 32 + lg * 8) * 2;
    bf16x8 bfr[4];
#pragma unroll
    for (int n = 0; n < 4; ++n) {
      int v   = n * 16 + lr;
      int off = v * (FLDSP * 2) + (ebyte ^ ((v & 28) << 2));
      bfr[n] = *reinterpret_cast<const bf16x8*>(BsRaw + off);
    }
#pragma unroll
    for (int m = 0; m < 2; ++m) {
      bf16x8 af = __builtin_bit_cast(bf16x8, a_raw[m][kq]);
#pragma unroll
      for (int n = 0; n < 4; ++n)
        acc[m][n] = __builtin_amdgcn_mfma_f32_16x16x32_bf16(af, bfr[n], acc[m][n], 0, 0, 0);
    }
  }

  size_t crow0 = (size_t)y * BM + r0;
#pragma unroll
  for (int m = 0; m < 2; ++m) {
#pragma unroll
    for (int n = 0; n < 4; ++n) {
      int colc = cbase + n * 16 + lr;
      if (colc < VOCAB) {
        float* cp = C + (crow0 + m * 16 + lg * 4) * (size_t)VOCAB + colc;
#pragma unroll
        for (int q = 0; q < 4; ++q)
          cp[(size_t)q * VOCAB] = acc[m][n][q];
      }
    }
  }
}

extern "C" void kernel_launch(void* const* d_in, const int* in_sizes, int n_in,
                              void* d_out, int out_size, void* d_ws, size_t ws_size,
                              hipStream_t stream) {
  const int*   idx    = (const int*)d_in[0];
  const float* W_proj = (const float*)d_in[1];
  const float* W_pred = (const float*)d_in[2];
  float*       out    = (float*)d_out;

  __hip_bfloat16* emb = (__hip_bfloat16*)d_ws;                 // 1 MB
  ushort* Btf = (ushort*)((char*)d_ws + (size_t)1048576);      // 12.9 MB
  const size_t needed = (size_t)1048576 + (size_t)VPAD * EMBED * 2;

  embed_bag_kernel<<<BATCH / 4, 256, 0, stream>>>(idx, W_proj, emb);

  if (ws_size >= needed) {
    transpose_b_kernel<<<NXT, 256, 0, stream>>>(W_pred, Btf);
    gemm4_kernel<<<768, 256, 0, stream>>>((const ushort*)emb, Btf, out);
  } else {
    int strips = (NXT + 7) / 8;
    int grid = 8 * strips * 32;
    gemm_kernel<<<grid, 256, 0, stream>>>(emb, W_pred, out);
  }
}